// Round 17
// baseline (100.993 us; speedup 1.0000x reference)
//
#include <hip/hip_runtime.h>
#include <stdint.h>

// SNN XOR net — verified recipe (R14, absmax=0.0), R17 = R16 with compile fix.
// Recipe (bit-exact, pinned):
//   cur  = (x0*w10) + (x1*w11)                 // no fma: two rounded products
//   m    = fmaf(0.9f, m, cur); m = m - s_prev; // fused mul-add, separate sub
//   s    = (m > 1.0f)
//   outv = ((s0*w20 + s1*w21) + s2*w22) + s3*w23
// R16 lesson: __builtin_nontemporal_store needs a NATIVE clang vector type,
// not HIP_vector_type<float,4> -> use ext_vector_type(4) float for the store.
// VEC=4 (16B/lane stores; R15's 8B stores regressed), spike-carry kept.

constexpr int T_STEPS = 20;
constexpr int H = 4;
constexpr int VEC = 4;   // 4 batch elements/thread -> 16B loads & stores

typedef float v4f __attribute__((ext_vector_type(4)));   // native vector for NT store

__global__ __launch_bounds__(256) void snn_r17_kernel(
    const float* __restrict__ x,    // f32 [B,2]
    const float* __restrict__ w1,   // f32 [4,2] row-major
    const float* __restrict__ w2,   // f32 [1,4]
    float* __restrict__ out,        // f32 [T,B]
    int B)
{
#pragma clang fp contract(off)
    const int tid = blockIdx.x * blockDim.x + threadIdx.x;
    if (tid * VEC >= B) return;

    float w1r[H][2], w2r[H];
#pragma unroll
    for (int h = 0; h < H; ++h) {
        w1r[h][0] = w1[2 * h];
        w1r[h][1] = w1[2 * h + 1];
        w2r[h]    = w2[h];
    }

    const float4 xa = reinterpret_cast<const float4*>(x)[2 * tid];
    const float4 xb = reinterpret_cast<const float4*>(x)[2 * tid + 1];
    const float xv[VEC][2] = {{xa.x, xa.y}, {xa.z, xa.w}, {xb.x, xb.y}, {xb.z, xb.w}};

    float cur[VEC][H], m1[VEC][H], s1[VEC][H], m2[VEC], s2[VEC];
#pragma unroll
    for (int l = 0; l < VEC; ++l) {
#pragma unroll
        for (int h = 0; h < H; ++h) {
            cur[l][h] = (xv[l][0] * w1r[h][0]) + (xv[l][1] * w1r[h][1]);
            m1[l][h] = 0.0f;
            s1[l][h] = 0.0f;
        }
        m2[l] = 0.0f;
        s2[l] = 0.0f;
    }

    v4f* const obase = reinterpret_cast<v4f*>(out) + tid;   // row stride B/4
    const size_t rowq = (size_t)B / 4;

#pragma unroll
    for (int t = 0; t < T_STEPS; ++t) {
        v4f o;
#pragma unroll
        for (int l = 0; l < VEC; ++l) {
#pragma unroll
            for (int h = 0; h < H; ++h) {
                float m = fmaf(0.9f, m1[l][h], cur[l][h]);  // fused mul-add
                m = m - s1[l][h];                           // separate subtract
                m1[l][h] = m;
                s1[l][h] = (m > 1.0f) ? 1.0f : 0.0f;        // spike & next reset
            }
            const float outv = ((s1[l][0] * w2r[0] + s1[l][1] * w2r[1])
                                + s1[l][2] * w2r[2]) + s1[l][3] * w2r[3];
            float m = fmaf(0.9f, m2[l], outv);
            m = m - s2[l];
            m2[l] = m;
            const float s = (m > 1.0f) ? 1.0f : 0.0f;
            s2[l] = s;
            o[l] = s;
        }
        // 16B/lane coalesced nontemporal store (output write-once, never read)
        __builtin_nontemporal_store(o, obase + (size_t)t * rowq);
    }
}

extern "C" void kernel_launch(void* const* d_in, const int* in_sizes, int n_in,
                              void* d_out, int out_size, void* d_ws, size_t ws_size,
                              hipStream_t stream) {
    const float* x  = (const float*)d_in[0];
    const float* w1 = (const float*)d_in[1];
    const float* w2 = (const float*)d_in[2];
    float* out = (float*)d_out;
    const int B = in_sizes[0] / 2;          // 1,048,576
    const int n_thr = B / VEC;              // 262,144 threads = 1024 blocks
    const int threads = 256;
    snn_r17_kernel<<<(n_thr + threads - 1) / threads, threads, 0, stream>>>(x, w1, w2, out, B);
}

// Round 18
// 98.035 us; speedup vs baseline: 1.0302x; 1.0302x over previous
//
#include <hip/hip_runtime.h>
#include <stdint.h>

// SNN XOR net — R18 = revert to R14 exactly (best measured: 96.99 us).
// Recipe (bit-exact, absmax=0.0 verified):
//   cur  = (x0*w10) + (x1*w11)                 // no fma: two rounded products
//   m    = fmaf(0.9f, m, cur); m = m - r;      // fused mul-add, separate sub
//   spk  = (m > 1.0f)
//   outv = ((p0 + p1) + p2) + p3,  p_h = spk_h ? w2_h : 0   // exact products
// Measured ladder: R14 (this config) 97.0 | R15 (VEC=2, 8B stores) 100.6 |
// R17 (NT stores) 101.0. Timed window dominated by harness 335MB poison fills
// at 6.1-6.4 TB/s (HBM roofline); kernel < 53 us (never in rocprof top-5),
// bounded ~15-20 us vs a 15 us write roofline -> addressable headroom ~5%.

constexpr int T_STEPS = 20;
constexpr int H = 4;
constexpr int VEC = 4;   // batch elements per thread -> float4 loads/stores

__global__ __launch_bounds__(256) void snn_r18_kernel(
    const float* __restrict__ x,    // f32 [B,2]
    const float* __restrict__ w1,   // f32 [4,2] row-major
    const float* __restrict__ w2,   // f32 [1,4]
    float* __restrict__ out,        // f32 [T,B]
    int B)
{
#pragma clang fp contract(off)
    const int tid = blockIdx.x * blockDim.x + threadIdx.x;
    if (tid * VEC >= B) return;

    float w1r[H][2], w2r[H];
#pragma unroll
    for (int h = 0; h < H; ++h) {
        w1r[h][0] = w1[2 * h];
        w1r[h][1] = w1[2 * h + 1];
        w2r[h]    = w2[h];
    }

    const float4 xa = reinterpret_cast<const float4*>(x)[2 * tid];
    const float4 xb = reinterpret_cast<const float4*>(x)[2 * tid + 1];
    const float xv[VEC][2] = {{xa.x, xa.y}, {xa.z, xa.w}, {xb.x, xb.y}, {xb.z, xb.w}};

    float cur[VEC][H], m1[VEC][H], m2[VEC];
#pragma unroll
    for (int l = 0; l < VEC; ++l) {
#pragma unroll
        for (int h = 0; h < H; ++h) {
            cur[l][h] = (xv[l][0] * w1r[h][0]) + (xv[l][1] * w1r[h][1]);
            m1[l][h] = 0.0f;
        }
        m2[l] = 0.0f;
    }

#pragma unroll
    for (int t = 0; t < T_STEPS; ++t) {
        float4 o; float* op = reinterpret_cast<float*>(&o);
#pragma unroll
        for (int l = 0; l < VEC; ++l) {
            float p[H];
#pragma unroll
            for (int h = 0; h < H; ++h) {
                float m = m1[l][h];
                const float r = (m > 1.0f) ? 1.0f : 0.0f;   // reset = prev spike
                m = fmaf(0.9f, m, cur[l][h]);               // fused mul-add
                m = m - r;                                  // separate subtract
                m1[l][h] = m;
                p[h] = (m > 1.0f) ? w2r[h] : 0.0f;          // s*w2, exact product
            }
            const float outv = ((p[0] + p[1]) + p[2]) + p[3];
            float m = m2[l];
            const float r = (m > 1.0f) ? 1.0f : 0.0f;
            m = fmaf(0.9f, m, outv);
            m = m - r;
            m2[l] = m;
            op[l] = (m > 1.0f) ? 1.0f : 0.0f;
        }
        reinterpret_cast<float4*>(out + (size_t)t * B)[tid] = o;   // coalesced 16B
    }
}

extern "C" void kernel_launch(void* const* d_in, const int* in_sizes, int n_in,
                              void* d_out, int out_size, void* d_ws, size_t ws_size,
                              hipStream_t stream) {
    const float* x  = (const float*)d_in[0];
    const float* w1 = (const float*)d_in[1];
    const float* w2 = (const float*)d_in[2];
    float* out = (float*)d_out;
    const int B = in_sizes[0] / 2;          // 1,048,576
    const int n_thr = B / VEC;              // 262,144 threads = 1024 blocks
    const int threads = 256;
    snn_r18_kernel<<<(n_thr + threads - 1) / threads, threads, 0, stream>>>(x, w1, w2, out, B);
}